// Round 6
// baseline (194.863 us; speedup 1.0000x reference)
//
#include <hip/hip_runtime.h>

#define JOINTS 24
#define NG 2                          // 64-batch groups per wave
#define WAVES 4
#define BLOCK_THREADS (WAVES * 64)
#define NSTEP (6 * NG)                // 6 chunks of 4 quats per group

__device__ constexpr int kParents[JOINTS] = {-1, 0, 0, 0, 1, 2, 3, 4, 5, 6, 7, 8,
                                             9, 9, 9, 12, 13, 14, 16, 17, 18, 19, 20, 21};

__device__ __forceinline__ void lgkm0_fence() {
    asm volatile("s_waitcnt lgkmcnt(0)" ::: "memory");
    __builtin_amdgcn_sched_barrier(0);
}

template <int J>
__device__ __forceinline__ void do_joint(float (*pos)[3], const float4 qj,
                                         const float* __restrict__ skel) {
    constexpr int P = kParents[J];
    const float ox = skel[J * 3 + 0] - skel[P * 3 + 0];
    const float oy = skel[J * 3 + 1] - skel[P * 3 + 1];
    const float oz = skel[J * 3 + 2] - skel[P * 3 + 2];
    const float w = qj.x, x = qj.y, y = qj.z, z = qj.w;
    const float r00 = 1.f - 2.f * (y * y + z * z);
    const float r01 = 2.f * (x * y - z * w);
    const float r02 = 2.f * (x * z + y * w);
    const float r10 = 2.f * (x * y + z * w);
    const float r11 = 1.f - 2.f * (x * x + z * z);
    const float r12 = 2.f * (y * z - x * w);
    const float r20 = 2.f * (x * z - y * w);
    const float r21 = 2.f * (y * z + x * w);
    const float r22 = 1.f - 2.f * (x * x + y * y);
    pos[J][0] = pos[P][0] + r00 * ox + r01 * oy + r02 * oz;
    pos[J][1] = pos[P][1] + r10 * ox + r11 * oy + r12 * oz;
    pos[J][2] = pos[P][2] + r20 * ox + r21 * oy + r22 * oz;
}

template <int C>  // joints 4C .. 4C+3 from q[0..3]
__device__ __forceinline__ void compute_chunk4(float (*pos)[3], const float4* q,
                                               const float* __restrict__ skel) {
    if constexpr (C == 0) {
        pos[0][0] = 0.f; pos[0][1] = 0.f; pos[0][2] = 0.f;
        do_joint<1>(pos, q[1], skel);
        do_joint<2>(pos, q[2], skel);
        do_joint<3>(pos, q[3], skel);
    } else {
        do_joint<4 * C + 0>(pos, q[0], skel);
        do_joint<4 * C + 1>(pos, q[1], skel);
        do_joint<4 * C + 2>(pos, q[2], skel);
        do_joint<4 * C + 3>(pos, q[3], skel);
    }
}

// Stage 64 batches x 4 quats (chunk c of group at gb) into `slice`,
// layout [batch][4quat] (lane's 4 quats contiguous). 4 glds, fire-and-forget.
__device__ __forceinline__ void issue_glds4(const float4* __restrict__ rot4,
                                            float4* slice, int gb, int lane, int c) {
#pragma unroll
    for (int k = 0; k < 4; ++k) {
        const int u = k * 64 + lane;          // unit this lane fills (linear)
        const int row = u >> 2, qq = u & 3;
        const float4* src = rot4 + ((size_t)(gb + row) * 24 + c * 4 + qq);
        __builtin_amdgcn_global_load_lds(
            (const __attribute__((address_space(1))) void*)src,
            (__attribute__((address_space(3))) void*)(slice + k * 64),
            16, 0, 0);
    }
}

// Output pass P: float4-columns [4P, 4P+NC) of all 64 batches through `slice`,
// then fully coalesced stores. NC=4 for P<4, NC=2 for P=4 (18 = 4*4+2).
template <int P>
__device__ __forceinline__ void store_pass(const float (*pos)[3], float4* slice,
                                           float4* __restrict__ out4, int gb, int lane) {
    constexpr int NC = (P < 4) ? 4 : 2;
    constexpr int C0 = 4 * P;
#pragma unroll
    for (int i = 0; i < NC; ++i) {
        float v[4];
#pragma unroll
        for (int t = 0; t < 4; ++t) {
            const int f = (C0 + i) * 4 + t;   // flat float 0..71, compile-time
            v[t] = pos[f / 3][f % 3];
        }
        slice[NC * lane + i] = make_float4(v[0], v[1], v[2], v[3]);
    }
    lgkm0_fence();                            // cross-lane write -> read
#pragma unroll
    for (int k = 0; k < NC; ++k) {
        const int u = k * 64 + lane;          // linear -> dense-ish stores
        const float4 vv = slice[u];
        const int row = (NC == 4) ? (u >> 2) : (u >> 1);
        const int col = (NC == 4) ? (u & 3) : (u & 1);
        out4[(size_t)(gb + row) * 18 + C0 + col] = vv;
    }
}

// Pipeline step T (chunk index in [0, NSTEP)): prefetch chunk T+1, counted
// wait for chunk T, transposed read + compute; at group end, 5 store passes
// through slice1 (just freed), then lgkm fence before slice1 is glds-reused.
template <int T>
__device__ __forceinline__ void step(const float4* __restrict__ rot4, float4* S,
                                     float4* __restrict__ out4, int wbase, int lane,
                                     float (*pos)[3], const float* __restrict__ skel) {
    constexpr int g = T / 6, c = T % 6;
    float4* cur = S + (T & 1) * 256;

    if constexpr (T + 1 < NSTEP) {
        __builtin_amdgcn_sched_barrier(0);
        issue_glds4(rot4, S + ((T + 1) & 1) * 256,
                    wbase + ((T + 1) / 6) * 64, lane, (T + 1) % 6);
    }

    // Static vmcnt accounting (4 glds/chunk, 18 stores per group burst):
    //  steady: chunk T is the oldest 4 of <=8 outstanding      -> vmcnt(4)
    //  T==6:   chunk6(4) + 18 group-0 stores + glds7(4) = 26   -> vmcnt(22)
    //  last:   drain                                           -> vmcnt(0)
    if constexpr (T == 6)              asm volatile("s_waitcnt vmcnt(22)" ::: "memory");
    else if constexpr (T + 1 == NSTEP) asm volatile("s_waitcnt vmcnt(0)" ::: "memory");
    else                               asm volatile("s_waitcnt vmcnt(4)" ::: "memory");
    __builtin_amdgcn_sched_barrier(0);

    float4 q[4];
#pragma unroll
    for (int j = 0; j < 4; ++j)
        q[j] = cur[4 * lane + j];             // lane's batch: contiguous 64B
    compute_chunk4<c>(pos, q, skel);

    if constexpr (c == 5) {                   // group done -> drain output
        float4* st = S + 256;                 // slice1 is free at both T=5,11
        const int gb = wbase + g * 64;
        store_pass<0>(pos, st, out4, gb, lane);
        store_pass<1>(pos, st, out4, gb, lane);
        store_pass<2>(pos, st, out4, gb, lane);
        store_pass<3>(pos, st, out4, gb, lane);
        store_pass<4>(pos, st, out4, gb, lane);
        lgkm0_fence();                        // reads done before glds reuse
    }
}

__global__ __launch_bounds__(BLOCK_THREADS, 4) void fk_kernel(
    const float* __restrict__ rot,      // [B, 24, 4]
    const float* __restrict__ skel,     // [24, 3]
    float* __restrict__ out,            // [B, 24, 3]
    int nB)
{
    __shared__ float4 lds[WAVES * 512];  // 32 KiB: per wave 2 slices x 4 KiB

    const int tid  = threadIdx.x;
    const int lane = tid & 63;
    const int wv   = tid >> 6;
    const int wbase = (blockIdx.x * WAVES + wv) * (NG * 64);

    float4* S = &lds[wv * 512];
    const float4* rot4 = reinterpret_cast<const float4*>(rot);
    float4* out4 = reinterpret_cast<float4*>(out);

    if (wbase + NG * 64 <= nB) {
        float pos[JOINTS][3];

        issue_glds4(rot4, S, wbase, lane, 0);      // prologue: chunk0 -> slice0

        step<0>(rot4, S, out4, wbase, lane, pos, skel);
        step<1>(rot4, S, out4, wbase, lane, pos, skel);
        step<2>(rot4, S, out4, wbase, lane, pos, skel);
        step<3>(rot4, S, out4, wbase, lane, pos, skel);
        step<4>(rot4, S, out4, wbase, lane, pos, skel);
        step<5>(rot4, S, out4, wbase, lane, pos, skel);
        step<6>(rot4, S, out4, wbase, lane, pos, skel);
        step<7>(rot4, S, out4, wbase, lane, pos, skel);
        step<8>(rot4, S, out4, wbase, lane, pos, skel);
        step<9>(rot4, S, out4, wbase, lane, pos, skel);
        step<10>(rot4, S, out4, wbase, lane, pos, skel);
        step<11>(rot4, S, out4, wbase, lane, pos, skel);
    } else {
        // Partial range (unused at B=524288): direct per-lane path.
#pragma unroll
        for (int g = 0; g < NG; ++g) {
            const int b = wbase + g * 64 + lane;
            if (b >= nB) continue;
            const float4* q4 = rot4 + (size_t)b * 24;
            float pos[JOINTS][3];
            pos[0][0] = 0.f; pos[0][1] = 0.f; pos[0][2] = 0.f;
#pragma unroll
            for (int j = 1; j < JOINTS; ++j) {
                const int p = kParents[j];
                const float ox = skel[j * 3 + 0] - skel[p * 3 + 0];
                const float oy = skel[j * 3 + 1] - skel[p * 3 + 1];
                const float oz = skel[j * 3 + 2] - skel[p * 3 + 2];
                const float4 qj = q4[j];
                const float w = qj.x, x = qj.y, y = qj.z, z = qj.w;
                const float r00 = 1.f - 2.f * (y * y + z * z);
                const float r01 = 2.f * (x * y - z * w);
                const float r02 = 2.f * (x * z + y * w);
                const float r10 = 2.f * (x * y + z * w);
                const float r11 = 1.f - 2.f * (x * x + z * z);
                const float r12 = 2.f * (y * z - x * w);
                const float r20 = 2.f * (x * z - y * w);
                const float r21 = 2.f * (y * z + x * w);
                const float r22 = 1.f - 2.f * (x * x + y * y);
                pos[j][0] = pos[p][0] + r00 * ox + r01 * oy + r02 * oz;
                pos[j][1] = pos[p][1] + r10 * ox + r11 * oy + r12 * oz;
                pos[j][2] = pos[p][2] + r20 * ox + r21 * oy + r22 * oz;
            }
            float* o = out + (size_t)b * 72;
#pragma unroll
            for (int j = 0; j < JOINTS; ++j) {
                o[j * 3 + 0] = pos[j][0];
                o[j * 3 + 1] = pos[j][1];
                o[j * 3 + 2] = pos[j][2];
            }
        }
    }
}

extern "C" void kernel_launch(void* const* d_in, const int* in_sizes, int n_in,
                              void* d_out, int out_size, void* d_ws, size_t ws_size,
                              hipStream_t stream) {
    const float* rot  = (const float*)d_in[0];   // [B, 24, 4] f32
    const float* skel = (const float*)d_in[1];   // [24, 3] f32
    float* out = (float*)d_out;                  // [B, 24, 3] f32

    const int B = in_sizes[0] / (JOINTS * 4);    // 524288
    const int perBlock = WAVES * NG * 64;        // 512 batches/block
    const int grid = (B + perBlock - 1) / perBlock;   // 1024 (= 4 per CU, resident)
    fk_kernel<<<grid, BLOCK_THREADS, 0, stream>>>(rot, skel, out, B);
}

// Round 7
// 76.345 us; speedup vs baseline: 2.5524x; 2.5524x over previous
//
#include <hip/hip_runtime.h>

// Pointer-jumping tables for the SMPL 24-joint tree.
// p1 = parent (root -> self), p2 = p1∘p1, p4 = p2∘p2.
// After rounds with p1,p2,p4 each joint holds the sum of itself + 7 nearest
// ancestors; every chain has <= 8 non-root nodes and the root's value is 0,
// so 3 rounds are exact.
__device__ __constant__ int cP1[24] = {0,0,0,0,1,2,3,4,5,6,7,8,9,9,9,12,13,14,16,17,18,19,20,21};
__device__ __constant__ int cP2[24] = {0,0,0,0,0,0,0,1,2,3,4,5,6,6,6,9,9,9,13,14,16,17,18,19};
__device__ __constant__ int cP4[24] = {0,0,0,0,0,0,0,0,0,0,0,0,0,0,0,3,3,3,6,6,9,9,13,14};

#define ITERS 16   // batches per 32-lane group per block

__global__ __launch_bounds__(256, 8) void fk_kernel(
    const float* __restrict__ rot,      // [B, 24, 4]
    const float* __restrict__ skel,     // [24, 3]
    float* __restrict__ out,            // [B, 24, 3]
    int B)
{
    const int tid = threadIdx.x;
    const int j   = tid & 31;           // joint lane within group
    const int grp = tid >> 5;           // 0..7 batch-groups per block
    const bool act = j < 24;
    const int jc  = act ? j : 0;

    const int p1 = cP1[jc];
    const int p2 = cP2[jc];
    const int p4 = cP4[jc];

    // Rest-pose bone offset (loop-invariant): skel[j] - skel[parent[j]].
    // Root: p1=0 -> offset 0 -> rotated contribution 0 (matches reference).
    const float sx = skel[jc * 3 + 0];
    const float sy = skel[jc * 3 + 1];
    const float sz = skel[jc * 3 + 2];
    const float ox = sx - __shfl(sx, p1, 32);
    const float oy = sy - __shfl(sy, p1, 32);
    const float oz = sz - __shfl(sz, p1, 32);

    const float4* __restrict__ rot4 = reinterpret_cast<const float4*>(rot);

    const int base = blockIdx.x * (8 * ITERS);   // first batch of this block

    // Software-pipelined batch loop: load for it+1 issued before compute of it.
    int b = base + grp;
    float4 q = make_float4(0.f, 0.f, 0.f, 0.f);
    if (act && b < B) q = rot4[(size_t)b * 24 + j];

    for (int it = 0; it < ITERS; ++it) {
        const int bn = base + (it + 1) * 8 + grp;
        float4 qn = make_float4(0.f, 0.f, 0.f, 0.f);
        if (it + 1 < ITERS && act && bn < B) qn = rot4[(size_t)bn * 24 + j];

        if (b < B) {
            // rotated[j] = R(q) @ offset   (no quat normalization, per reference)
            const float w = q.x, x = q.y, y = q.z, z = q.w;
            float vx = (1.f - 2.f * (y * y + z * z)) * ox
                     + (2.f * (x * y - z * w)) * oy
                     + (2.f * (x * z + y * w)) * oz;
            float vy = (2.f * (x * y + z * w)) * ox
                     + (1.f - 2.f * (x * x + z * z)) * oy
                     + (2.f * (y * z - x * w)) * oz;
            float vz = (2.f * (x * z - y * w)) * ox
                     + (2.f * (y * z + x * w)) * oy
                     + (1.f - 2.f * (x * x + y * y)) * oz;

            // Tree prefix-sum: 3 pointer-jumping rounds (exact, see tables).
            float ax = vx + __shfl(vx, p1, 32);
            float ay = vy + __shfl(vy, p1, 32);
            float az = vz + __shfl(vz, p1, 32);

            float bx = ax + __shfl(ax, p2, 32);
            float by = ay + __shfl(ay, p2, 32);
            float bz = az + __shfl(az, p2, 32);

            float cx = bx + __shfl(bx, p4, 32);
            float cy = by + __shfl(by, p4, 32);
            float cz = bz + __shfl(bz, p4, 32);

            if (act) {
                float* o = out + (size_t)b * 72 + j * 3;
                o[0] = cx; o[1] = cy; o[2] = cz;
            }
        }
        q = qn;
        b = bn;
    }
}

extern "C" void kernel_launch(void* const* d_in, const int* in_sizes, int n_in,
                              void* d_out, int out_size, void* d_ws, size_t ws_size,
                              hipStream_t stream) {
    const float* rot  = (const float*)d_in[0];   // [B, 24, 4] f32
    const float* skel = (const float*)d_in[1];   // [24, 3] f32
    float* out = (float*)d_out;                  // [B, 24, 3] f32

    const int B = in_sizes[0] / (24 * 4);        // 524288
    const int perBlock = 8 * ITERS;              // 128 batches per block
    const int grid = (B + perBlock - 1) / perBlock;   // 4096
    fk_kernel<<<grid, 256, 0, stream>>>(rot, skel, out, B);
}

// Round 9
// 58.806 us; speedup vs baseline: 3.3136x; 1.2982x over previous
//
#include <hip/hip_runtime.h>

typedef float floatx4 __attribute__((ext_vector_type(4)));

// Pointer-jumping tables for the SMPL 24-joint tree.
// p1 = parent (root -> self), p2 = p1∘p1, p4 = p2∘p2.
// Every chain has <= 8 non-root nodes and the root's rotated value is 0,
// so 3 rounds (p1, p2, p4) give the exact ancestor-chain sum.
__device__ __constant__ int cP1[24] = {0,0,0,0,1,2,3,4,5,6,7,8,9,9,9,12,13,14,16,17,18,19,20,21};
__device__ __constant__ int cP2[24] = {0,0,0,0,0,0,0,1,2,3,4,5,6,6,6,9,9,9,13,14,16,17,18,19};
__device__ __constant__ int cP4[24] = {0,0,0,0,0,0,0,0,0,0,0,0,0,0,0,3,3,3,6,6,9,9,13,14};

#define ITERS 16   // batches per 32-lane group per block

__global__ __launch_bounds__(256, 8) void fk_kernel(
    const float* __restrict__ rot,      // [B, 24, 4]
    const float* __restrict__ skel,     // [24, 3]
    float* __restrict__ out,            // [B, 24, 3]
    int B)
{
    const int tid = threadIdx.x;
    const int j   = tid & 31;           // joint lane within 32-lane group
    const int grp = tid >> 5;           // 0..7 batch-groups per block
    const bool act = j < 24;
    const int jc  = act ? j : 0;

    const int p1 = cP1[jc];
    const int p2 = cP2[jc];
    const int p4 = cP4[jc];

    // Repack constants: dest lane j (if j<18) stores floats [4j, 4j+4) of its
    // group's 72-float output; source lanes sA=(4j)/3, sA+1; case r=j%3.
    const int sA = (4 * j) / 3;
    const int sB = (sA < 23) ? sA + 1 : 23;
    const int r  = j % 3;

    // Rest-pose bone offset (loop-invariant): skel[j] - skel[parent[j]].
    const float sx = skel[jc * 3 + 0];
    const float sy = skel[jc * 3 + 1];
    const float sz = skel[jc * 3 + 2];
    const float ox = sx - __shfl(sx, p1, 32);
    const float oy = sy - __shfl(sy, p1, 32);
    const float oz = sz - __shfl(sz, p1, 32);

    const float4* __restrict__ rot4 = reinterpret_cast<const float4*>(rot);
    floatx4* __restrict__ out4 = reinterpret_cast<floatx4*>(out);

    const int base = blockIdx.x * (8 * ITERS);   // first batch of this block

    // Software-pipelined batch loop: load for it+1 issued before compute of it.
    int b = base + grp;
    float4 q = make_float4(0.f, 0.f, 0.f, 0.f);
    if (act && b < B) q = rot4[(size_t)b * 24 + j];

    for (int it = 0; it < ITERS; ++it) {
        const int bn = base + (it + 1) * 8 + grp;
        float4 qn = make_float4(0.f, 0.f, 0.f, 0.f);
        if (it + 1 < ITERS && act && bn < B) qn = rot4[(size_t)bn * 24 + j];

        if (b < B) {
            // rotated[j] = R(q) @ offset   (no quat normalization, per reference)
            const float w = q.x, x = q.y, y = q.z, z = q.w;
            float vx = (1.f - 2.f * (y * y + z * z)) * ox
                     + (2.f * (x * y - z * w)) * oy
                     + (2.f * (x * z + y * w)) * oz;
            float vy = (2.f * (x * y + z * w)) * ox
                     + (1.f - 2.f * (x * x + z * z)) * oy
                     + (2.f * (y * z - x * w)) * oz;
            float vz = (2.f * (x * z - y * w)) * ox
                     + (2.f * (y * z + x * w)) * oy
                     + (1.f - 2.f * (x * x + y * y)) * oz;

            // Tree prefix-sum: 3 pointer-jumping rounds (exact).
            float ax = vx + __shfl(vx, p1, 32);
            float ay = vy + __shfl(vy, p1, 32);
            float az = vz + __shfl(vz, p1, 32);

            float bx = ax + __shfl(ax, p2, 32);
            float by = ay + __shfl(ay, p2, 32);
            float bz = az + __shfl(az, p2, 32);

            float cx = bx + __shfl(bx, p4, 32);
            float cy = by + __shfl(by, p4, 32);
            float cz = bz + __shfl(bz, p4, 32);

            // In-wave repack: lanes 0..17 of each group gather one float4 of
            // the group's [24 joints x 3] output (6 shuffles + 8 selects).
            const float axA = __shfl(cx, sA, 32), ayA = __shfl(cy, sA, 32), azA = __shfl(cz, sA, 32);
            const float axB = __shfl(cx, sB, 32), ayB = __shfl(cy, sB, 32), azB = __shfl(cz, sB, 32);

            const float o0 = (r == 0) ? axA : (r == 1) ? ayA : azA;
            const float o1 = (r == 0) ? ayA : (r == 1) ? azA : axB;
            const float o2 = (r == 0) ? azA : (r == 1) ? axB : ayB;
            const float o3 = (r == 0) ? axB : (r == 1) ? ayB : azB;

            // Dense, fully-covered, 64B-aligned wave store; nontemporal so the
            // output bypasses L2/L3 and the input stays L3-resident.
            if (j < 18) {
                floatx4 v; v.x = o0; v.y = o1; v.z = o2; v.w = o3;
                __builtin_nontemporal_store(v, out4 + (size_t)b * 18 + j);
            }
        }
        q = qn;
        b = bn;
    }
}

extern "C" void kernel_launch(void* const* d_in, const int* in_sizes, int n_in,
                              void* d_out, int out_size, void* d_ws, size_t ws_size,
                              hipStream_t stream) {
    const float* rot  = (const float*)d_in[0];   // [B, 24, 4] f32
    const float* skel = (const float*)d_in[1];   // [24, 3] f32
    float* out = (float*)d_out;                  // [B, 24, 3] f32

    const int B = in_sizes[0] / (24 * 4);        // 524288
    const int perBlock = 8 * ITERS;              // 128 batches per block
    const int grid = (B + perBlock - 1) / perBlock;   // 4096
    fk_kernel<<<grid, 256, 0, stream>>>(rot, skel, out, B);
}